// Round 4
// baseline (597.373 us; speedup 1.0000x reference)
//
#include <hip/hip_runtime.h>
#include <stdint.h>

#define TK_F       4096
#define TK_THREADS 256
#define TK_R       16                             // rows per block (software pipeline)
#define TK_NBINS   2048                           // top-11-bit histogram
#define TK_HSLOTS  (TK_NBINS + (TK_NBINS >> 5))   // 2112: +1 dword pad per 32 bins
#define TK_CAP     256                            // threshold-bin candidates (~26 expected)

// order-preserving float<->uint transforms
__device__ __forceinline__ unsigned int tk_f2u(unsigned int b) {
    return b ^ ((unsigned int)(((int)b) >> 31) | 0x80000000u);
}
__device__ __forceinline__ unsigned int tk_u2f(unsigned int u) {
    return u ^ ((~(unsigned int)(((int)u) >> 31)) | 0x80000000u);
}
// padded slot: atomic bank spread by mantissa low bits; strided scan reads 2 lanes/bank
__device__ __forceinline__ unsigned int tk_slot(unsigned int b) {
    return b + (b >> 5);
}

// RAW barrier: LDS visibility only. NO vmcnt drain -> prefetch loads stay in flight.
#define TK_BAR() do {                                          \
    asm volatile("s_waitcnt lgkmcnt(0)" ::: "memory");         \
    __builtin_amdgcn_s_barrier();                              \
    asm volatile("" ::: "memory");                             \
} while (0)

// One row's processing. U holds the row's 16 raw words on entry; at the end,
// row RR+2 is prefetched into U (loads cross the next row's barriers).
#define TK_BODY(U, RR) do {                                                         \
    const int  row = rowBase + (RR);                                                \
    const bool rv  = (row < B);                                                     \
    const size_t rbase = (size_t)(rv ? row : (B - 1)) * TK_F;                       \
    /* phase A: transform in place + histogram (counted vmcnt lands here) */        \
    _Pragma("unroll")                                                               \
    for (int e = 0; e < 16; ++e) {                                                  \
        const unsigned int uu = tk_f2u(U[e]);                                       \
        U[e] = uu;                                                                  \
        atomicAdd(&hist[tk_slot(uu >> 21)], 1u);                                    \
    }                                                                               \
    TK_BAR(); /* B1: histogram complete */                                          \
    /* phase B: per-thread 8-bin sums + wave suffix scan */                         \
    unsigned int hbin[8]; unsigned int s = 0;                                       \
    { const unsigned int sb = tk_slot((unsigned int)tid * 8u);                      \
      _Pragma("unroll")                                                             \
      for (int j = 0; j < 8; ++j) { hbin[j] = hist[sb + j]; s += hbin[j]; } }       \
    unsigned int acc = s;                                                           \
    _Pragma("unroll")                                                               \
    for (int d = 1; d < 64; d <<= 1) {                                              \
        const unsigned int t_ = (unsigned int)__shfl_down((int)acc, d, 64);         \
        if (lane + d < 64) acc += t_;                                               \
    }                                                                               \
    if (lane == 0) ((unsigned int*)&waveTotV)[wid] = acc;                           \
    TK_BAR(); /* B2: wave totals visible */                                         \
    { const uint4 wt = waveTotV;                                                    \
      unsigned int later = 0;                                                       \
      if (wid < 3) later += wt.w;                                                   \
      if (wid < 2) later += wt.z;                                                   \
      if (wid < 1) later += wt.y;                                                   \
      unsigned int run = later + (acc - s);                                         \
      _Pragma("unroll")                                                             \
      for (int j = 7; j >= 0; --j) {                                                \
          const unsigned int h = hbin[j];                                           \
          if (run < k && run + h >= k) { sh_b = tid * 8 + j; sh_cum = run; }        \
          run += h;                                                                 \
      }                                                                             \
      if (tid == 0) sh_cnt = 0u; /* safe: prior row's readers passed B5 long ago */ \
    }                                                                               \
    TK_BAR(); /* B3: threshold bin id visible, cnt reset */                         \
    {                                                                               \
      const int          bb  = sh_b;                                                \
      const unsigned int cum = sh_cum;                                              \
      /* collect: per-thread pack, 1 atomic (rarely 2+) per thread */               \
      unsigned int c0 = 0, c1 = 0, nm = 0;                                          \
      _Pragma("unroll")                                                             \
      for (int e = 0; e < 16; ++e) {                                                \
          const unsigned int uu = U[e];                                             \
          if ((int)(uu >> 21) == bb) {                                              \
              if (nm == 0u) c0 = uu;                                                \
              else if (nm == 1u) c1 = uu;                                           \
              else { const unsigned int p = atomicAdd(&sh_cnt, 1u);                 \
                     if (p < TK_CAP) cand[p] = uu; }                                \
              ++nm;                                                                 \
          }                                                                         \
      }                                                                             \
      if (nm) {                                                                     \
          const unsigned int take = nm < 2u ? nm : 2u;                              \
          const unsigned int p0 = atomicAdd(&sh_cnt, take);                         \
          if (p0 < TK_CAP) cand[p0] = c0;                                           \
          if (take > 1u && p0 + 1u < TK_CAP) cand[p0 + 1u] = c1;                    \
      }                                                                             \
      /* clear histogram for the NEXT row (its reads finished before B2) */         \
      const uint4 z4 = make_uint4(0u, 0u, 0u, 0u);                                  \
      hist4[tid] = z4; hist4[tid + 256] = z4;                                       \
      if (tid < (TK_HSLOTS / 4 - 512)) hist4[512 + tid] = z4;                       \
      TK_BAR(); /* B4: candidates complete, hist cleared */                         \
      const unsigned int L  = sh_cnt < TK_CAP ? sh_cnt : TK_CAP;                    \
      const unsigned int rk = k - cum;                                              \
      for (unsigned int j = (unsigned int)tid; j < L; j += TK_THREADS) {            \
          const unsigned int uj = cand[j];                                          \
          unsigned int g = 0, eq = 0;                                               \
          for (unsigned int i = 0; i < L; ++i) {                                    \
              const unsigned int ui = cand[i];                                      \
              g  += (ui > uj)  ? 1u : 0u;                                           \
              eq += (ui == uj) ? 1u : 0u;                                           \
          }                                                                         \
          if (g < rk && g + eq >= rk) { sh_T = uj; sh_g = g; sh_e = eq; }           \
      }                                                                             \
      TK_BAR(); /* B5: threshold visible */                                         \
      const unsigned int T  = sh_T;                                                 \
      const unsigned int re = rk - sh_g;                                            \
      const bool easy = (sh_e == re);                                               \
      unsigned int*       orow = (unsigned int*)(out + rbase);                      \
      const unsigned int* xr   = (const unsigned int*)(x + rbase);                  \
      _Pragma("unroll")                                                             \
      for (int v = 0; v < 4; ++v) {                                                 \
          uint4 q;                                                                  \
          _Pragma("unroll")                                                         \
          for (int j = 0; j < 4; ++j) {                                             \
              const unsigned int uu = U[v*4 + j];                                   \
              unsigned int val = 0u;                                                \
              if (uu > T) {                                                         \
                  val = tk_u2f(uu);                                                 \
              } else if (uu == T) {                                                 \
                  if (easy) { val = tk_u2f(uu); }                                   \
                  else {                                                            \
                      /* rare: tie straddles the cut -> lowest indices win */       \
                      const int idx = (tid + v * TK_THREADS) * 4 + j;               \
                      unsigned int c2 = 0;                                          \
                      for (int i = 0; i < idx; ++i)                                 \
                          c2 += (tk_f2u(xr[i]) == T) ? 1u : 0u;                     \
                      if (c2 < re) val = tk_u2f(uu);                                \
                  }                                                                 \
              }                                                                     \
              (&q.x)[j] = val;                                                      \
          }                                                                         \
          if (rv) ((uint4*)orow)[tid + v * TK_THREADS] = q;                         \
      }                                                                             \
      /* prefetch row RR+2 into U: in flight across the next row's barriers */      \
      if ((RR) + 2 < TK_R) {                                                        \
          int prow = rowBase + (RR) + 2; if (prow >= B) prow = B - 1;               \
          const uint4* pv = (const uint4*)(x + (size_t)prow * TK_F);                \
          _Pragma("unroll")                                                         \
          for (int v = 0; v < 4; ++v) {                                             \
              const uint4 q = pv[tid + v * TK_THREADS];                             \
              U[v*4+0] = q.x; U[v*4+1] = q.y; U[v*4+2] = q.z; U[v*4+3] = q.w;       \
          }                                                                         \
      }                                                                             \
    }                                                                               \
} while (0)

__global__ __launch_bounds__(TK_THREADS, 4)   // 4 blocks/CU: grid 1024 fully resident
void tk_topk_mask(const float* __restrict__ x, const int* __restrict__ kp,
                  float* __restrict__ out, int B)
{
    __shared__ uint4        hist4[TK_HSLOTS / 4];   // 8448 B
    __shared__ unsigned int cand[TK_CAP];           // 1024 B
    __shared__ uint4        waveTotV;
    __shared__ unsigned int sh_cnt;
    __shared__ int          sh_b;
    __shared__ unsigned int sh_cum, sh_T, sh_g, sh_e;

    const int tid  = (int)threadIdx.x;
    const int lane = tid & 63;
    const int wid  = tid >> 6;
    const int rowBase = (int)blockIdx.x * TK_R;
    if (rowBase >= B) return;
    const unsigned int k = (unsigned int)kp[0];
    unsigned int* hist = (unsigned int*)hist4;

    if (k == 0u || k >= TK_F) {                 // degenerate: zeros or copy-all
        for (int r = 0; r < TK_R; ++r) {
            const int row = rowBase + r;
            if (row >= B) break;
            const uint4* xv = (const uint4*)(x + (size_t)row * TK_F);
            uint4*       ov = (uint4*)(out + (size_t)row * TK_F);
            #pragma unroll
            for (int v = 0; v < 4; ++v) {
                uint4 q = make_uint4(0u, 0u, 0u, 0u);
                if (k) q = xv[tid + v * TK_THREADS];
                ov[tid + v * TK_THREADS] = q;
            }
        }
        return;
    }

    // prologue: clear LDS state; issue loads for rows 0 and 1 (raw bits)
    {
        const uint4 z4 = make_uint4(0u, 0u, 0u, 0u);
        hist4[tid] = z4; hist4[tid + 256] = z4;
        if (tid < (TK_HSLOTS / 4 - 512)) hist4[512 + tid] = z4;
        if (tid == 0) sh_cnt = 0u;
    }
    unsigned int uA[16], uB[16];
    {
        int r0 = rowBase;             if (r0 >= B) r0 = B - 1;
        int r1 = rowBase + 1;         if (r1 >= B) r1 = B - 1;
        const uint4* p0 = (const uint4*)(x + (size_t)r0 * TK_F);
        const uint4* p1 = (const uint4*)(x + (size_t)r1 * TK_F);
        #pragma unroll
        for (int v = 0; v < 4; ++v) {
            const uint4 qa = p0[tid + v * TK_THREADS];
            uA[v*4+0] = qa.x; uA[v*4+1] = qa.y; uA[v*4+2] = qa.z; uA[v*4+3] = qa.w;
        }
        #pragma unroll
        for (int v = 0; v < 4; ++v) {
            const uint4 qb = p1[tid + v * TK_THREADS];
            uB[v*4+0] = qb.x; uB[v*4+1] = qb.y; uB[v*4+2] = qb.z; uB[v*4+3] = qb.w;
        }
    }
    TK_BAR();   // B0: LDS clear visible (loads remain in flight)

    #pragma unroll
    for (int rr = 0; rr < TK_R; rr += 2) {
        TK_BODY(uA, rr);
        TK_BODY(uB, rr + 1);
    }
}

extern "C" void kernel_launch(void* const* d_in, const int* in_sizes, int n_in,
                              void* d_out, int out_size, void* d_ws, size_t ws_size,
                              hipStream_t stream) {
    const float* x   = (const float*)d_in[0];
    const int*   kp  = (const int*)d_in[1];
    float*       out = (float*)d_out;
    const int B = in_sizes[0] / TK_F;
    hipLaunchKernelGGL(tk_topk_mask, dim3((B + TK_R - 1) / TK_R), dim3(TK_THREADS),
                       0, stream, x, kp, out, B);
}